// Round 16
// baseline (675.128 us; speedup 1.0000x reference)
//
#include <hip/hip_runtime.h>
#include <math.h>

#define TQ_LEN 2048
#define TKV_LEN 4096
#define BATCH 4
#define DMODEL 1024
#define NH 16
#define HD 64
#define NKBA 1152   // 1024 (k) + 16 (beta) + 16 (alpha) + 96 pad
#define CCH 128     // scan chunk length
#define NCHUNK (TKV_LEN / CCH)   // 32 chunks per (b,h)

typedef unsigned short u16;
typedef __attribute__((ext_vector_type(8))) short bf16x8;
typedef __attribute__((ext_vector_type(4))) float f32x4;

__device__ __forceinline__ u16 f2bf(float x) {
  union { float f; unsigned u; } c; c.f = x;
  unsigned r = c.u + 0x7fffu + ((c.u >> 16) & 1u);
  return (u16)(r >> 16);
}
__device__ __forceinline__ float bf2f(u16 x) {
  union { unsigned u; float f; } c; c.u = ((unsigned)x) << 16;
  return c.f;
}

__device__ __forceinline__ float wave_sum64(float x) {
#pragma unroll
  for (int off = 32; off; off >>= 1) x += __shfl_xor(x, off, 64);
  return x;
}

// ---- fp32 -> bf16 cast, 8 elems/thread, exact grid (n % 2048 == 0) ----
__global__ __launch_bounds__(256) void cvt_bf16_kernel(
    const float* __restrict__ s, u16* __restrict__ d) {
  size_t i = ((size_t)blockIdx.x * 256 + threadIdx.x) * 8;
  float4 a = *(const float4*)&s[i];
  float4 b = *(const float4*)&s[i + 4];
  union { u16 h[8]; uint4 v; } o;
  o.h[0] = f2bf(a.x); o.h[1] = f2bf(a.y); o.h[2] = f2bf(a.z); o.h[3] = f2bf(a.w);
  o.h[4] = f2bf(b.x); o.h[5] = f2bf(b.y); o.h[6] = f2bf(b.z); o.h[7] = f2bf(b.w);
  *(uint4*)&d[i] = o.v;
}

// ---- build concatenated bf16 weight [Wk; Wbeta; Walpha; zeros] : [1152,1024] ----
__global__ __launch_bounds__(256) void wcat_bf_kernel(
    const float* __restrict__ Wk, const float* __restrict__ Wb,
    const float* __restrict__ Wa, u16* __restrict__ Wcat) {
  int i = blockIdx.x * 256 + threadIdx.x;
  int row = i / DMODEL, col = i % DMODEL;
  float v;
  if (row < 1024)      v = Wk[i];
  else if (row < 1040) v = Wb[(row - 1024) * DMODEL + col];
  else if (row < 1056) v = Wa[(row - 1040) * DMODEL + col];
  else                 v = 0.f;
  Wcat[i] = f2bf(v);
}

// ---- bf16 MFMA GEMM (m97 structure): C[M,N] = A[M,K] * B[N,K]^T (+bias) ----
// 1-D grid + XCD-aware bijective block swizzle (T1). Requires gridDim.x%8==0.
__device__ __forceinline__ void stage_tile_bf16(
    const u16* __restrict__ G, int ldg, int row0, int kcol0,
    u16* lds, int wid, int lane) {
#pragma unroll
  for (int e = 0; e < 2; ++e) {
    int r = (wid * 2 + e) * 16;
    const u16* g = G + (size_t)(row0 + r + (lane >> 2)) * ldg + kcol0 + (lane & 3) * 8;
    __builtin_amdgcn_global_load_lds(
        (const __attribute__((address_space(1))) void*)g,
        (__attribute__((address_space(3))) void*)(lds + r * 32), 16, 0, 0);
  }
}

template <bool HAS_BIAS, bool OUT_BF16>
__global__ __launch_bounds__(256) void gemm_bt_bf16(
    const u16* __restrict__ A, const u16* __restrict__ B,
    const float* __restrict__ bias, void* __restrict__ Cv,
    int M, int N, int K, int ldc, int nbx) {
  __shared__ u16 Al[2][128 * 32];
  __shared__ u16 Bl[2][128 * 32];
  const int tid = threadIdx.x;
  const int wid = tid >> 6, lane = tid & 63;
  const int wr = wid >> 1, wc = wid & 1;  // wave -> 64x64 quadrant
  const int nwg = gridDim.x;
  const int cpx = nwg >> 3;
  const int orig = blockIdx.x;
  const int swz = (orig & 7) * cpx + (orig >> 3);
  const int bm = (swz / nbx) * 128, bn = (swz % nbx) * 128;
  const int lrow = lane & 15, lk = (lane >> 4) * 8;

  int aoff[4], boff[4];
#pragma unroll
  for (int f = 0; f < 4; ++f) {
    aoff[f] = (wr * 64 + f * 16 + lrow) * 32 + lk;
    boff[f] = (wc * 64 + f * 16 + lrow) * 32 + lk;
  }

  f32x4 acc[4][4] = {};
  const int nk = K >> 5;
  int cur = 0;
  stage_tile_bf16(A, K, bm, 0, &Al[0][0], wid, lane);
  stage_tile_bf16(B, K, bn, 0, &Bl[0][0], wid, lane);
  __syncthreads();
  for (int kt = 0; kt < nk; ++kt) {
    if (kt + 1 < nk) {
      stage_tile_bf16(A, K, bm, (kt + 1) * 32, &Al[cur ^ 1][0], wid, lane);
      stage_tile_bf16(B, K, bn, (kt + 1) * 32, &Bl[cur ^ 1][0], wid, lane);
    }
    bf16x8 af[4], bfr[4];
#pragma unroll
    for (int f = 0; f < 4; ++f) af[f] = *(const bf16x8*)&Al[cur][aoff[f]];
#pragma unroll
    for (int f = 0; f < 4; ++f) bfr[f] = *(const bf16x8*)&Bl[cur][boff[f]];
#pragma unroll
    for (int mf = 0; mf < 4; ++mf)
#pragma unroll
      for (int nf = 0; nf < 4; ++nf)
        acc[mf][nf] = __builtin_amdgcn_mfma_f32_16x16x32_bf16(
            af[mf], bfr[nf], acc[mf][nf], 0, 0, 0);
    __syncthreads();
    cur ^= 1;
  }
  const int crow0 = bm + wr * 64 + (lane >> 4) * 4;
  const int ccol0 = bn + wc * 64 + (lane & 15);
#pragma unroll
  for (int mf = 0; mf < 4; ++mf)
#pragma unroll
    for (int nf = 0; nf < 4; ++nf) {
      int col = ccol0 + nf * 16;
      float bv = HAS_BIAS ? bias[col] : 0.f;
#pragma unroll
      for (int i = 0; i < 4; ++i) {
        int row = crow0 + mf * 16 + i;
        float vout = acc[mf][nf][i] + bv;
        if (OUT_BF16)
          ((u16*)Cv)[(size_t)row * ldc + col] = f2bf(vout);
        else
          ((float*)Cv)[(size_t)row * ldc + col] = vout;
      }
    }
}

// ======== FUSED: q-GEMM + chunk scan in ONE dispatch (r16) ========
// Rationale: scan is latency-pinned at 136us with 18% occupancy (>80% of
// the chip idle); the q-projection GEMM is data-independent of the scan
// (scan reads kba/vpb/beta/alpha; q-GEMM reads qbf/Wq only). One stream =
// serial dispatches, so overlap requires one kernel. Blocks [0,nscan) run
// the scan (4 INDEPENDENT chunk-waves/block, r14-validated packaging around
// the byte-identical r5 inner loop, fp32 stores); blocks [nscan, nscan+512)
// run the m97 q-GEMM body. Scan blocks placed FIRST (long pole launches
// first under typical ascending dispatch). MFMA and VALU pipes co-schedule
// (m114). Both branches byte-identical math to r15 -> absmax unchanged.
__global__ __launch_bounds__(256) void fused_qgemm_scan_kernel(
    const u16* __restrict__ qbf, const u16* __restrict__ Wq_bf,
    float* __restrict__ qp,
    const float* __restrict__ kb, const u16* __restrict__ v,
    const float* __restrict__ beta, const float* __restrict__ alpha,
    float* __restrict__ Pbuf, float* __restrict__ Sbuf, int nscan) {
  __shared__ u16 Al[2][128 * 32];
  __shared__ u16 Bl[2][128 * 32];
  __shared__ float klds[4][2][64];

  if ((int)blockIdx.x >= nscan) {
    // ---------------- q GEMM branch (M=8192, N=K=ldc=1024) ----------------
    const int tid = threadIdx.x;
    const int wid = tid >> 6, lane = tid & 63;
    const int wr = wid >> 1, wc = wid & 1;
    const int nwg = gridDim.x - nscan;          // 512, %8==0
    const int cpx = nwg >> 3;
    const int orig = (int)blockIdx.x - nscan;
    const int swz = (orig & 7) * cpx + (orig >> 3);
    const int nbx = DMODEL / 128;               // 8
    const int bm = (swz / nbx) * 128, bn = (swz % nbx) * 128;
    const int lrow = lane & 15, lk = (lane >> 4) * 8;

    int aoff[4], boff[4];
#pragma unroll
    for (int f = 0; f < 4; ++f) {
      aoff[f] = (wr * 64 + f * 16 + lrow) * 32 + lk;
      boff[f] = (wc * 64 + f * 16 + lrow) * 32 + lk;
    }

    f32x4 acc[4][4] = {};
    const int nk = DMODEL >> 5;
    int cur = 0;
    stage_tile_bf16(qbf, DMODEL, bm, 0, &Al[0][0], wid, lane);
    stage_tile_bf16(Wq_bf, DMODEL, bn, 0, &Bl[0][0], wid, lane);
    __syncthreads();
    for (int kt = 0; kt < nk; ++kt) {
      if (kt + 1 < nk) {
        stage_tile_bf16(qbf, DMODEL, bm, (kt + 1) * 32, &Al[cur ^ 1][0], wid, lane);
        stage_tile_bf16(Wq_bf, DMODEL, bn, (kt + 1) * 32, &Bl[cur ^ 1][0], wid, lane);
      }
      bf16x8 af[4], bfr[4];
#pragma unroll
      for (int f = 0; f < 4; ++f) af[f] = *(const bf16x8*)&Al[cur][aoff[f]];
#pragma unroll
      for (int f = 0; f < 4; ++f) bfr[f] = *(const bf16x8*)&Bl[cur][boff[f]];
#pragma unroll
      for (int mf = 0; mf < 4; ++mf)
#pragma unroll
        for (int nf = 0; nf < 4; ++nf)
          acc[mf][nf] = __builtin_amdgcn_mfma_f32_16x16x32_bf16(
              af[mf], bfr[nf], acc[mf][nf], 0, 0, 0);
      __syncthreads();
      cur ^= 1;
    }
    const int crow0 = bm + wr * 64 + (lane >> 4) * 4;
    const int ccol0 = bn + wc * 64 + (lane & 15);
#pragma unroll
    for (int mf = 0; mf < 4; ++mf)
#pragma unroll
      for (int nf = 0; nf < 4; ++nf) {
        int col = ccol0 + nf * 16;
#pragma unroll
        for (int i = 0; i < 4; ++i) {
          int row = crow0 + mf * 16 + i;
          qp[(size_t)row * DMODEL + col] = acc[mf][nf][i];
        }
      }
  } else {
    // ---------------- scan branch: 4 independent chunk-waves --------------
    int wid = threadIdx.x >> 6;
    int lane = threadIdx.x & 63;
    int slot = (int)blockIdx.x * 4 + wid;   // 0 .. 2047
    int bh = slot / NCHUNK, ck = slot % NCHUNK;
    int b = bh >> 4, h = bh & 15;
    int t0 = ck * CCH;
    const float* kbase = kb + ((size_t)b * TKV_LEN + t0) * NKBA + h * HD;
    const u16* vbase = v + ((size_t)b * TKV_LEN + t0) * DMODEL + h * HD;
    const float* bbase = beta + ((size_t)b * TKV_LEN + t0) * NH + h;
    const float* abase = alpha + ((size_t)b * TKV_LEN + t0) * NH + h;

    float P[64], S[64];
#pragma unroll
    for (int j = 0; j < 64; ++j) { P[j] = (j == lane) ? 1.f : 0.f; S[j] = 0.f; }

    klds[wid][0][lane] = kbase[lane];
    float kn = kbase[(size_t)NKBA + lane];
    float vn = bf2f(vbase[lane]);
    float btn = bbase[0];
    float atn = abase[0];

    for (int t = 0; t < CCH; ++t) {
      float vc = vn, bt = btn, at = atn;
      if (t + 1 < CCH) {
        vn = bf2f(vbase[(size_t)(t + 1) * DMODEL + lane]);
        btn = bbase[(size_t)(t + 1) * NH];
        atn = abase[(size_t)(t + 1) * NH];
      }
      klds[wid][(t + 1) & 1][lane] = kn;
      kn = (t + 2 < CCH) ? kbase[(size_t)(t + 2) * NKBA + lane] : 0.f;
      const float* kcur = klds[wid][t & 1];
      float pk0 = 0.f, pk1 = 0.f, sk0 = 0.f, sk1 = 0.f;
#pragma unroll
      for (int g = 0; g < 4; ++g) {
        float4 ka = *(const float4*)&kcur[g * 16 + 0];
        float4 kc = *(const float4*)&kcur[g * 16 + 4];
        float4 ke = *(const float4*)&kcur[g * 16 + 8];
        float4 kg = *(const float4*)&kcur[g * 16 + 12];
        pk0 = fmaf(P[g*16+ 0], ka.x, pk0); pk1 = fmaf(P[g*16+ 1], ka.y, pk1);
        pk0 = fmaf(P[g*16+ 2], ka.z, pk0); pk1 = fmaf(P[g*16+ 3], ka.w, pk1);
        pk0 = fmaf(P[g*16+ 4], kc.x, pk0); pk1 = fmaf(P[g*16+ 5], kc.y, pk1);
        pk0 = fmaf(P[g*16+ 6], kc.z, pk0); pk1 = fmaf(P[g*16+ 7], kc.w, pk1);
        pk0 = fmaf(P[g*16+ 8], ke.x, pk0); pk1 = fmaf(P[g*16+ 9], ke.y, pk1);
        pk0 = fmaf(P[g*16+10], ke.z, pk0); pk1 = fmaf(P[g*16+11], ke.w, pk1);
        pk0 = fmaf(P[g*16+12], kg.x, pk0); pk1 = fmaf(P[g*16+13], kg.y, pk1);
        pk0 = fmaf(P[g*16+14], kg.z, pk0); pk1 = fmaf(P[g*16+15], kg.w, pk1);
        sk0 = fmaf(S[g*16+ 0], ka.x, sk0); sk1 = fmaf(S[g*16+ 1], ka.y, sk1);
        sk0 = fmaf(S[g*16+ 2], ka.z, sk0); sk1 = fmaf(S[g*16+ 3], ka.w, sk1);
        sk0 = fmaf(S[g*16+ 4], kc.x, sk0); sk1 = fmaf(S[g*16+ 5], kc.y, sk1);
        sk0 = fmaf(S[g*16+ 6], kc.z, sk0); sk1 = fmaf(S[g*16+ 7], kc.w, sk1);
        sk0 = fmaf(S[g*16+ 8], ke.x, sk0); sk1 = fmaf(S[g*16+ 9], ke.y, sk1);
        sk0 = fmaf(S[g*16+10], ke.z, sk0); sk1 = fmaf(S[g*16+11], ke.w, sk1);
        sk0 = fmaf(S[g*16+12], kg.x, sk0); sk1 = fmaf(S[g*16+13], kg.y, sk1);
        sk0 = fmaf(S[g*16+14], kg.z, sk0); sk1 = fmaf(S[g*16+15], kg.w, sk1);
      }
      float cp = -at * (pk0 + pk1);
      float cs = fmaf(bt, vc, -at * (sk0 + sk1));
#pragma unroll
      for (int g = 0; g < 4; ++g) {
        float4 ka = *(const float4*)&kcur[g * 16 + 0];
        float4 kc = *(const float4*)&kcur[g * 16 + 4];
        float4 ke = *(const float4*)&kcur[g * 16 + 8];
        float4 kg = *(const float4*)&kcur[g * 16 + 12];
        P[g*16+ 0] = fmaf(cp, ka.x, P[g*16+ 0]); P[g*16+ 1] = fmaf(cp, ka.y, P[g*16+ 1]);
        P[g*16+ 2] = fmaf(cp, ka.z, P[g*16+ 2]); P[g*16+ 3] = fmaf(cp, ka.w, P[g*16+ 3]);
        P[g*16+ 4] = fmaf(cp, kc.x, P[g*16+ 4]); P[g*16+ 5] = fmaf(cp, kc.y, P[g*16+ 5]);
        P[g*16+ 6] = fmaf(cp, kc.z, P[g*16+ 6]); P[g*16+ 7] = fmaf(cp, kc.w, P[g*16+ 7]);
        P[g*16+ 8] = fmaf(cp, ke.x, P[g*16+ 8]); P[g*16+ 9] = fmaf(cp, ke.y, P[g*16+ 9]);
        P[g*16+10] = fmaf(cp, ke.z, P[g*16+10]); P[g*16+11] = fmaf(cp, ke.w, P[g*16+11]);
        P[g*16+12] = fmaf(cp, kg.x, P[g*16+12]); P[g*16+13] = fmaf(cp, kg.y, P[g*16+13]);
        P[g*16+14] = fmaf(cp, kg.z, P[g*16+14]); P[g*16+15] = fmaf(cp, kg.w, P[g*16+15]);
        S[g*16+ 0] = fmaf(cs, ka.x, S[g*16+ 0]); S[g*16+ 1] = fmaf(cs, ka.y, S[g*16+ 1]);
        S[g*16+ 2] = fmaf(cs, ka.z, S[g*16+ 2]); S[g*16+ 3] = fmaf(cs, ka.w, S[g*16+ 3]);
        S[g*16+ 4] = fmaf(cs, kc.x, S[g*16+ 4]); S[g*16+ 5] = fmaf(cs, kc.y, S[g*16+ 5]);
        S[g*16+ 6] = fmaf(cs, kc.z, S[g*16+ 6]); S[g*16+ 7] = fmaf(cs, kc.w, S[g*16+ 7]);
        S[g*16+ 8] = fmaf(cs, ke.x, S[g*16+ 8]); S[g*16+ 9] = fmaf(cs, ke.y, S[g*16+ 9]);
        S[g*16+10] = fmaf(cs, ke.z, S[g*16+10]); S[g*16+11] = fmaf(cs, ke.w, S[g*16+11]);
        S[g*16+12] = fmaf(cs, kg.x, S[g*16+12]); S[g*16+13] = fmaf(cs, kg.y, S[g*16+13]);
        S[g*16+14] = fmaf(cs, kg.z, S[g*16+14]); S[g*16+15] = fmaf(cs, kg.w, S[g*16+15]);
      }
    }
    float* po = Pbuf + (size_t)slot * 4096 + (size_t)lane * 64;
    float* so = Sbuf + (size_t)slot * 4096 + (size_t)lane * 64;
#pragma unroll
    for (int j4 = 0; j4 < 16; ++j4) {
      *(float4*)&po[j4 * 4] = make_float4(P[4 * j4], P[4 * j4 + 1], P[4 * j4 + 2], P[4 * j4 + 3]);
      *(float4*)&so[j4 * 4] = make_float4(S[4 * j4], S[4 * j4 + 1], S[4 * j4 + 2], S[4 * j4 + 3]);
    }
  }
}

// ---- per-(token,head) LayerNorm on q (in place) ----
__global__ __launch_bounds__(256) void ln_q_kernel(float* __restrict__ q,
                                                   const float* __restrict__ g,
                                                   const float* __restrict__ b) {
  int gidx = blockIdx.x * 4 + (threadIdx.x >> 6);
  int lane = threadIdx.x & 63;
  int row = gidx >> 4, h = gidx & 15;
  float* p = q + (size_t)row * DMODEL + h * HD + lane;
  float x = *p;
  float mu = wave_sum64(x) * (1.f / 64.f);
  float d = x - mu;
  float var = wave_sum64(d * d) * (1.f / 64.f);
  float y = d * rsqrtf(var + 1e-5f) * g[lane] + b[lane];
  *p = y;
}

// ---- LayerNorm + L2 normalize on k (in place, inside kba buffer) ----
__global__ __launch_bounds__(256) void ln_k_kernel(float* __restrict__ kb,
                                                   const float* __restrict__ g,
                                                   const float* __restrict__ b) {
  int gidx = blockIdx.x * 4 + (threadIdx.x >> 6);
  int lane = threadIdx.x & 63;
  int row = gidx >> 4, h = gidx & 15;
  float* p = kb + (size_t)row * NKBA + h * HD + lane;
  float x = *p;
  float mu = wave_sum64(x) * (1.f / 64.f);
  float d = x - mu;
  float var = wave_sum64(d * d) * (1.f / 64.f);
  float y = d * rsqrtf(var + 1e-5f) * g[lane] + b[lane];
  float s2 = wave_sum64(y * y);
  y = y / fmaxf(sqrtf(s2), 1e-12f);
  *p = y;
}

// ---- sigmoid(logit + bias) -> compact beta/alpha [B*TKV, 16] ----
__global__ __launch_bounds__(256) void sig_kernel(
    const float* __restrict__ kb, const float* __restrict__ bb,
    const float* __restrict__ ba, float* __restrict__ beta,
    float* __restrict__ alpha) {
  int i = blockIdx.x * 256 + threadIdx.x;
  int row = i >> 4, h = i & 15;
  float lb = kb[(size_t)row * NKBA + 1024 + h] + bb[h];
  float la = kb[(size_t)row * NKBA + 1040 + h] + ba[h];
  beta[i]  = 1.f / (1.f + expf(-lb));
  alpha[i] = 1.f / (1.f + expf(-la));
}

// ---- phase 2: fold nitems chunk pairs: (P,S) <- (P*Pc, S*Pc + Sc) ----
__global__ __launch_bounds__(256) void fold_kernel(
    const float* __restrict__ Pin, const float* __restrict__ Sin,
    float* __restrict__ Pout, float* __restrict__ Sout, int nitems) {
  __shared__ float Pa[64][68], Sa[64][68], Pc[64][68], Sc[64][68];
  const int tid = threadIdx.x;
  const int r0 = (tid >> 4) * 4, c0 = (tid & 15) * 4;
  for (int l = tid; l < 4096; l += 256) {
    int r = l >> 6, c = l & 63;
    Pa[r][c] = (r == c) ? 1.f : 0.f;
    Sa[r][c] = 0.f;
  }
  for (int item = 0; item < nitems; ++item) {
    const float* pg = Pin + ((size_t)blockIdx.x * nitems + item) * 4096;
    const float* sg = Sin + ((size_t)blockIdx.x * nitems + item) * 4096;
#pragma unroll
    for (int e = 0; e < 4; ++e) {
      int l = tid * 16 + e * 4;
      int r = l >> 6, c = l & 63;
      *(float4*)&Pc[r][c] = *(const float4*)&pg[l];
      *(float4*)&Sc[r][c] = *(const float4*)&sg[l];
    }
    __syncthreads();
    float accP[4][4] = {}, accS[4][4] = {};
#pragma unroll 4
    for (int j4 = 0; j4 < 16; ++j4) {
      float bmat[4][4];
#pragma unroll
      for (int jj = 0; jj < 4; ++jj) {
        float4 t = *(const float4*)&Pc[j4 * 4 + jj][c0];
        bmat[jj][0] = t.x; bmat[jj][1] = t.y; bmat[jj][2] = t.z; bmat[jj][3] = t.w;
      }
#pragma unroll
      for (int rr = 0; rr < 4; ++rr) {
        float4 tp = *(const float4*)&Pa[r0 + rr][j4 * 4];
        float4 ts = *(const float4*)&Sa[r0 + rr][j4 * 4];
        float ap[4] = {tp.x, tp.y, tp.z, tp.w};
        float as[4] = {ts.x, ts.y, ts.z, ts.w};
#pragma unroll
        for (int jj = 0; jj < 4; ++jj)
#pragma unroll
          for (int cc = 0; cc < 4; ++cc) {
            accP[rr][cc] = fmaf(ap[jj], bmat[jj][cc], accP[rr][cc]);
            accS[rr][cc] = fmaf(as[jj], bmat[jj][cc], accS[rr][cc]);
          }
      }
    }
#pragma unroll
    for (int rr = 0; rr < 4; ++rr)
#pragma unroll
      for (int cc = 0; cc < 4; ++cc) accS[rr][cc] += Sc[r0 + rr][c0 + cc];
    __syncthreads();
#pragma unroll
    for (int rr = 0; rr < 4; ++rr)
#pragma unroll
      for (int cc = 0; cc < 4; ++cc) {
        Pa[r0 + rr][c0 + cc] = accP[rr][cc];
        Sa[r0 + rr][c0 + cc] = accS[rr][cc];
      }
  }
  __syncthreads();
  float* po = Pout + (size_t)blockIdx.x * 4096;
  float* so = Sout + (size_t)blockIdx.x * 4096;
#pragma unroll
  for (int e = 0; e < 4; ++e) {
    int l = tid * 16 + e * 4;
    int r = l >> 6, c = l & 63;
    *(float4*)&po[l] = *(const float4*)&Pa[r][c];
    *(float4*)&so[l] = *(const float4*)&Sa[r][c];
  }
}

// ---- attn[b,t,h,i] = sum_j M[b,h,i,j] * q[b,t,h,j]  (bf16 out) ----
__global__ __launch_bounds__(256) void outm_kernel(
    const float* __restrict__ Mg, const float* __restrict__ q,
    u16* __restrict__ attn) {
  __shared__ float Ml[64][65];
  int bh = blockIdx.x;
  int tchunk = blockIdx.y;
  int b = bh >> 4, h = bh & 15;
  int tid = threadIdx.x;
  const float* mg = Mg + (size_t)bh * 4096;
#pragma unroll
  for (int e = 0; e < 16; ++e) {
    int l = tid + e * 256;
    Ml[l >> 6][l & 63] = mg[l];
  }
  __syncthreads();
  int lane = tid & 63, tt = tid >> 6;
  const float* qb = q + ((size_t)b * TQ_LEN + tchunk * 256) * DMODEL + h * HD;
  u16* ob = attn + ((size_t)b * TQ_LEN + tchunk * 256) * DMODEL + h * HD;
  for (int it = 0; it < 64; ++it) {
    int t = it * 4 + tt;
    const float* qr = qb + (size_t)t * DMODEL;
    float acc = 0.f;
#pragma unroll
    for (int j4 = 0; j4 < 16; ++j4) {
      float4 qv = *(const float4*)&qr[j4 * 4];
      acc += Ml[lane][j4 * 4 + 0] * qv.x + Ml[lane][j4 * 4 + 1] * qv.y +
             Ml[lane][j4 * 4 + 2] * qv.z + Ml[lane][j4 * 4 + 3] * qv.w;
    }
    ob[(size_t)t * DMODEL + lane] = f2bf(acc);
  }
}

extern "C" void kernel_launch(void* const* d_in, const int* in_sizes, int n_in,
                              void* d_out, int out_size, void* d_ws,
                              size_t ws_size, hipStream_t stream) {
  const float* query = (const float*)d_in[0];
  const float* key   = (const float*)d_in[1];
  const float* value = (const float*)d_in[2];
  const float* Wq    = (const float*)d_in[3];
  const float* Wk    = (const float*)d_in[4];
  const float* Wv    = (const float*)d_in[5];
  const float* Wo    = (const float*)d_in[6];
  const float* bo    = (const float*)d_in[7];
  const float* Wbeta = (const float*)d_in[8];
  const float* bbeta = (const float*)d_in[9];
  const float* Walpha= (const float*)d_in[10];
  const float* balpha= (const float*)d_in[11];
  const float* gq    = (const float*)d_in[12];
  const float* bq    = (const float*)d_in[13];
  const float* gk    = (const float*)d_in[14];
  const float* bk    = (const float*)d_in[15];
  float* out = (float*)d_out;

  const int MQ = BATCH * TQ_LEN;    // 8192
  const int MKV = BATCH * TKV_LEN;  // 16384
  const int NSLOT = 64 * NCHUNK;    // 2048

  // Workspace layout (float units). Peak 58,523,648 floats = 234.1 MB
  // (< proven-available 260.6 MB). beta/alpha moved to tail: with the fused
  // kernel, sig runs BEFORE the q-GEMM reads qbf, so they can no longer
  // overlay qbf. Gp/Gs/Fp/Mg stay in qbf overlay (written post-fusion).
  float* ws = (float*)d_ws;
  size_t off = 0;
  u16* Wcat_bf = (u16*)(ws + off); off += (size_t)NKBA * DMODEL / 2;   // 589824
  u16* Wq_bf   = (u16*)(ws + off); off += (size_t)DMODEL * DMODEL / 2; // 262144
  u16* Wv_bf   = (u16*)(ws + off); off += (size_t)DMODEL * DMODEL / 2;
  u16* Wo_bf   = (u16*)(ws + off); off += (size_t)DMODEL * DMODEL / 2;
  u16* qbf = (u16*)(ws + off); size_t qbf_f = off; off += (size_t)MQ * DMODEL / 2;   // 4194304
  u16* kbf = (u16*)(ws + off); size_t kbf_f = off; off += (size_t)MKV * DMODEL / 2;  // 8388608
  u16* vbf = (u16*)(ws + off); size_t vbf_f = off; off += (size_t)MKV * DMODEL / 2;  // 8388608
  float* qp   = ws + off; off += (size_t)MQ * DMODEL;                  // 8388608
  float* kba  = ws + off; size_t kba_f = off; off += (size_t)MKV * NKBA; // 18874368
  u16* vpb = (u16*)(ws + off); off += (size_t)MKV * DMODEL / 2;        // 8388608
  float* beta = ws + off; off += (size_t)MKV * NH;                     // 262144
  float* alpha= ws + off; off += (size_t)MKV * NH;                     // 262144
  // overlays on dead regions:
  float* Pbuf = ws + kbf_f;                    // over kbf (dead after k GEMM)
  float* Sbuf = ws + vbf_f;                    // over vbf (dead after v GEMM)
  float* Gp   = ws + qbf_f;                    // 1048576 ┐ over qbf (dead after
  float* Gs   = ws + qbf_f + 1048576;          // 1048576 │ the FUSED kernel's
  float* Fp   = ws + qbf_f + 2097152;          //  262144 │ q-GEMM branch)
  float* Mg   = ws + qbf_f + 2359296;          //  262144 ┘
  u16* attn_bf = (u16*)(ws + kba_f);           // over kba (dead after scan)

  // 1. weight + input casts
  wcat_bf_kernel<<<NKBA * DMODEL / 256, 256, 0, stream>>>(Wk, Wbeta, Walpha, Wcat_bf);
  cvt_bf16_kernel<<<DMODEL * DMODEL / 2048, 256, 0, stream>>>(Wq, Wq_bf);
  cvt_bf16_kernel<<<DMODEL * DMODEL / 2048, 256, 0, stream>>>(Wv, Wv_bf);
  cvt_bf16_kernel<<<DMODEL * DMODEL / 2048, 256, 0, stream>>>(Wo, Wo_bf);
  cvt_bf16_kernel<<<MQ * DMODEL / 2048, 256, 0, stream>>>(query, qbf);
  cvt_bf16_kernel<<<MKV * DMODEL / 2048, 256, 0, stream>>>(key, kbf);
  cvt_bf16_kernel<<<MKV * DMODEL / 2048, 256, 0, stream>>>(value, vbf);
  // 2. k/v projections (bf16 MFMA; 1-D grid, XCD swizzle, nwg % 8 == 0)
  gemm_bt_bf16<false, false><<<(NKBA / 128) * (MKV / 128), 256, 0, stream>>>(
      kbf, Wcat_bf, nullptr, kba, MKV, NKBA, DMODEL, NKBA, NKBA / 128);
  gemm_bt_bf16<false, true><<<(DMODEL / 128) * (MKV / 128), 256, 0, stream>>>(
      vbf, Wv_bf, nullptr, vpb, MKV, DMODEL, DMODEL, DMODEL, DMODEL / 128);
  // 3. k-norm + gates (scan inputs ready after this)
  ln_k_kernel<<<MKV * NH / 4, 256, 0, stream>>>(kba, gk, bk);
  sig_kernel<<<MKV * NH / 256, 256, 0, stream>>>(kba, bbeta, balpha, beta, alpha);
  // 4. FUSED: scan (blocks 0..511, 4 chunk-waves each) + q GEMM (512..1023)
  fused_qgemm_scan_kernel<<<NSLOT / 4 + (DMODEL / 128) * (MQ / 128), 256, 0,
                            stream>>>(qbf, Wq_bf, qp, kba, vpb, beta, alpha,
                                      Pbuf, Sbuf, NSLOT / 4);
  // 5. q-norm, folds
  ln_q_kernel<<<MQ * NH / 4, 256, 0, stream>>>(qp, gq, bq);
  fold_kernel<<<NSLOT / 8, 256, 0, stream>>>(Pbuf, Sbuf, Gp, Gs, 8);
  fold_kernel<<<64, 256, 0, stream>>>(Gp, Gs, Fp, Mg, 4);
  // 6. attn = q @ M^T per (b,h)  (bf16 out, over dead kba)
  outm_kernel<<<dim3(64, TQ_LEN / 256), 256, 0, stream>>>(Mg, qp, attn_bf);
  // 7. out = attn @ Wo^T + bo
  gemm_bt_bf16<true, false><<<(DMODEL / 128) * (MQ / 128), 256, 0, stream>>>(
      attn_bf, Wo_bf, bo, out, MQ, DMODEL, DMODEL, DMODEL, DMODEL / 128);
  (void)in_sizes; (void)n_in; (void)out_size; (void)ws_size;
}

// Round 17
// 583.842 us; speedup vs baseline: 1.1564x; 1.1564x over previous
//
#include <hip/hip_runtime.h>
#include <math.h>

#define TQ_LEN 2048
#define TKV_LEN 4096
#define BATCH 4
#define DMODEL 1024
#define NH 16
#define HD 64
#define NKBA 1152   // 1024 (k) + 16 (beta) + 16 (alpha) + 96 pad
#define CCH 128     // scan chunk length
#define NCHUNK (TKV_LEN / CCH)   // 32 chunks per (b,h)

typedef unsigned short u16;
typedef __attribute__((ext_vector_type(8))) short bf16x8;
typedef __attribute__((ext_vector_type(4))) float f32x4;

__device__ __forceinline__ u16 f2bf(float x) {
  union { float f; unsigned u; } c; c.f = x;
  unsigned r = c.u + 0x7fffu + ((c.u >> 16) & 1u);
  return (u16)(r >> 16);
}
__device__ __forceinline__ float bf2f(u16 x) {
  union { unsigned u; float f; } c; c.u = ((unsigned)x) << 16;
  return c.f;
}

__device__ __forceinline__ float wave_sum64(float x) {
#pragma unroll
  for (int off = 32; off; off >>= 1) x += __shfl_xor(x, off, 64);
  return x;
}

// ---- fp32 -> bf16 cast, 8 elems/thread, exact grid (n % 2048 == 0) ----
__global__ __launch_bounds__(256) void cvt_bf16_kernel(
    const float* __restrict__ s, u16* __restrict__ d) {
  size_t i = ((size_t)blockIdx.x * 256 + threadIdx.x) * 8;
  float4 a = *(const float4*)&s[i];
  float4 b = *(const float4*)&s[i + 4];
  union { u16 h[8]; uint4 v; } o;
  o.h[0] = f2bf(a.x); o.h[1] = f2bf(a.y); o.h[2] = f2bf(a.z); o.h[3] = f2bf(a.w);
  o.h[4] = f2bf(b.x); o.h[5] = f2bf(b.y); o.h[6] = f2bf(b.z); o.h[7] = f2bf(b.w);
  *(uint4*)&d[i] = o.v;
}

// ---- build concatenated bf16 weight [Wk; Wbeta; Walpha; zeros] : [1152,1024] ----
__global__ __launch_bounds__(256) void wcat_bf_kernel(
    const float* __restrict__ Wk, const float* __restrict__ Wb,
    const float* __restrict__ Wa, u16* __restrict__ Wcat) {
  int i = blockIdx.x * 256 + threadIdx.x;
  int row = i / DMODEL, col = i % DMODEL;
  float v;
  if (row < 1024)      v = Wk[i];
  else if (row < 1040) v = Wb[(row - 1024) * DMODEL + col];
  else if (row < 1056) v = Wa[(row - 1040) * DMODEL + col];
  else                 v = 0.f;
  Wcat[i] = f2bf(v);
}

// ---- bf16 MFMA GEMM (m97 structure): C[M,N] = A[M,K] * B[N,K]^T (+bias) ----
// 1-D grid + XCD-aware bijective block swizzle (T1). Requires gridDim.x%8==0.
__device__ __forceinline__ void stage_tile_bf16(
    const u16* __restrict__ G, int ldg, int row0, int kcol0,
    u16* lds, int wid, int lane) {
#pragma unroll
  for (int e = 0; e < 2; ++e) {
    int r = (wid * 2 + e) * 16;
    const u16* g = G + (size_t)(row0 + r + (lane >> 2)) * ldg + kcol0 + (lane & 3) * 8;
    __builtin_amdgcn_global_load_lds(
        (const __attribute__((address_space(1))) void*)g,
        (__attribute__((address_space(3))) void*)(lds + r * 32), 16, 0, 0);
  }
}

template <bool HAS_BIAS, bool OUT_BF16>
__global__ __launch_bounds__(256) void gemm_bt_bf16(
    const u16* __restrict__ A, const u16* __restrict__ B,
    const float* __restrict__ bias, void* __restrict__ Cv,
    int M, int N, int K, int ldc, int nbx) {
  __shared__ u16 Al[2][128 * 32];
  __shared__ u16 Bl[2][128 * 32];
  const int tid = threadIdx.x;
  const int wid = tid >> 6, lane = tid & 63;
  const int wr = wid >> 1, wc = wid & 1;  // wave -> 64x64 quadrant
  const int nwg = gridDim.x;
  const int cpx = nwg >> 3;
  const int orig = blockIdx.x;
  const int swz = (orig & 7) * cpx + (orig >> 3);
  const int bm = (swz / nbx) * 128, bn = (swz % nbx) * 128;
  const int lrow = lane & 15, lk = (lane >> 4) * 8;

  int aoff[4], boff[4];
#pragma unroll
  for (int f = 0; f < 4; ++f) {
    aoff[f] = (wr * 64 + f * 16 + lrow) * 32 + lk;
    boff[f] = (wc * 64 + f * 16 + lrow) * 32 + lk;
  }

  f32x4 acc[4][4] = {};
  const int nk = K >> 5;
  int cur = 0;
  stage_tile_bf16(A, K, bm, 0, &Al[0][0], wid, lane);
  stage_tile_bf16(B, K, bn, 0, &Bl[0][0], wid, lane);
  __syncthreads();
  for (int kt = 0; kt < nk; ++kt) {
    if (kt + 1 < nk) {
      stage_tile_bf16(A, K, bm, (kt + 1) * 32, &Al[cur ^ 1][0], wid, lane);
      stage_tile_bf16(B, K, bn, (kt + 1) * 32, &Bl[cur ^ 1][0], wid, lane);
    }
    bf16x8 af[4], bfr[4];
#pragma unroll
    for (int f = 0; f < 4; ++f) af[f] = *(const bf16x8*)&Al[cur][aoff[f]];
#pragma unroll
    for (int f = 0; f < 4; ++f) bfr[f] = *(const bf16x8*)&Bl[cur][boff[f]];
#pragma unroll
    for (int mf = 0; mf < 4; ++mf)
#pragma unroll
      for (int nf = 0; nf < 4; ++nf)
        acc[mf][nf] = __builtin_amdgcn_mfma_f32_16x16x32_bf16(
            af[mf], bfr[nf], acc[mf][nf], 0, 0, 0);
    __syncthreads();
    cur ^= 1;
  }
  // C/D layout: col = lane&15, row = (lane>>4)*4 + i
  const int crow0 = bm + wr * 64 + (lane >> 4) * 4;
  const int ccol0 = bn + wc * 64 + (lane & 15);
#pragma unroll
  for (int mf = 0; mf < 4; ++mf)
#pragma unroll
    for (int nf = 0; nf < 4; ++nf) {
      int col = ccol0 + nf * 16;
      float bv = HAS_BIAS ? bias[col] : 0.f;
#pragma unroll
      for (int i = 0; i < 4; ++i) {
        int row = crow0 + mf * 16 + i;
        float vout = acc[mf][nf][i] + bv;
        if (OUT_BF16)
          ((u16*)Cv)[(size_t)row * ldc + col] = f2bf(vout);
        else
          ((float*)Cv)[(size_t)row * ldc + col] = vout;
      }
    }
}

// ---- per-(token,head) LayerNorm on q (in place) ----
__global__ __launch_bounds__(256) void ln_q_kernel(float* __restrict__ q,
                                                   const float* __restrict__ g,
                                                   const float* __restrict__ b) {
  int gidx = blockIdx.x * 4 + (threadIdx.x >> 6);
  int lane = threadIdx.x & 63;
  int row = gidx >> 4, h = gidx & 15;
  float* p = q + (size_t)row * DMODEL + h * HD + lane;
  float x = *p;
  float mu = wave_sum64(x) * (1.f / 64.f);
  float d = x - mu;
  float var = wave_sum64(d * d) * (1.f / 64.f);
  float y = d * rsqrtf(var + 1e-5f) * g[lane] + b[lane];
  *p = y;
}

// ---- LayerNorm + L2 normalize on k (in place, inside kba buffer) ----
__global__ __launch_bounds__(256) void ln_k_kernel(float* __restrict__ kb,
                                                   const float* __restrict__ g,
                                                   const float* __restrict__ b) {
  int gidx = blockIdx.x * 4 + (threadIdx.x >> 6);
  int lane = threadIdx.x & 63;
  int row = gidx >> 4, h = gidx & 15;
  float* p = kb + (size_t)row * NKBA + h * HD + lane;
  float x = *p;
  float mu = wave_sum64(x) * (1.f / 64.f);
  float d = x - mu;
  float var = wave_sum64(d * d) * (1.f / 64.f);
  float y = d * rsqrtf(var + 1e-5f) * g[lane] + b[lane];
  float s2 = wave_sum64(y * y);
  y = y / fmaxf(sqrtf(s2), 1e-12f);
  *p = y;
}

// ---- sigmoid(logit + bias) -> compact beta/alpha [B*TKV, 16] ----
__global__ __launch_bounds__(256) void sig_kernel(
    const float* __restrict__ kb, const float* __restrict__ bb,
    const float* __restrict__ ba, float* __restrict__ beta,
    float* __restrict__ alpha) {
  int i = blockIdx.x * 256 + threadIdx.x;
  int row = i >> 4, h = i & 15;
  float lb = kb[(size_t)row * NKBA + 1024 + h] + bb[h];
  float la = kb[(size_t)row * NKBA + 1040 + h] + ba[h];
  beta[i]  = 1.f / (1.f + expf(-lb));
  alpha[i] = 1.f / (1.f + expf(-la));
}

// ---- phase 1: per-chunk transition (P = prod A_t, S = zero-start scan) ----
// ROUND-5 PROVEN FORM (136 us). Scan is latency-pinned: 8 variants
// (fused-update r9, 2-wave split r6-r8, CCH=64 r13, 4-wave pack r14,
// qGEMM-fusion r16) all landed 133-304 us; none beat this. Closed.
__global__ __launch_bounds__(64, 2) void chunk_scan_kernel(
    const float* __restrict__ kb, const u16* __restrict__ v,
    const float* __restrict__ beta, const float* __restrict__ alpha,
    float* __restrict__ Pbuf, float* __restrict__ Sbuf) {
  __shared__ float klds[2][64];
  int slot = blockIdx.x;
  int bh = slot / NCHUNK, ck = slot % NCHUNK;
  int b = bh >> 4, h = bh & 15;
  int lane = threadIdx.x;
  int t0 = ck * CCH;
  const float* kbase = kb + ((size_t)b * TKV_LEN + t0) * NKBA + h * HD;
  const u16* vbase = v + ((size_t)b * TKV_LEN + t0) * DMODEL + h * HD;
  const float* bbase = beta + ((size_t)b * TKV_LEN + t0) * NH + h;
  const float* abase = alpha + ((size_t)b * TKV_LEN + t0) * NH + h;

  float P[64], S[64];
#pragma unroll
  for (int j = 0; j < 64; ++j) { P[j] = (j == lane) ? 1.f : 0.f; S[j] = 0.f; }

  klds[0][lane] = kbase[lane];
  float kn = kbase[(size_t)NKBA + lane];
  float vn = bf2f(vbase[lane]);
  float btn = bbase[0];
  float atn = abase[0];

  for (int t = 0; t < CCH; ++t) {
    float vc = vn, bt = btn, at = atn;
    if (t + 1 < CCH) {
      vn = bf2f(vbase[(size_t)(t + 1) * DMODEL + lane]);
      btn = bbase[(size_t)(t + 1) * NH];
      atn = abase[(size_t)(t + 1) * NH];
    }
    klds[(t + 1) & 1][lane] = kn;
    kn = (t + 2 < CCH) ? kbase[(size_t)(t + 2) * NKBA + lane] : 0.f;
    const float* kcur = klds[t & 1];
    float pk0 = 0.f, pk1 = 0.f, sk0 = 0.f, sk1 = 0.f;
#pragma unroll
    for (int g = 0; g < 4; ++g) {
      float4 ka = *(const float4*)&kcur[g * 16 + 0];
      float4 kc = *(const float4*)&kcur[g * 16 + 4];
      float4 ke = *(const float4*)&kcur[g * 16 + 8];
      float4 kg = *(const float4*)&kcur[g * 16 + 12];
      pk0 = fmaf(P[g*16+ 0], ka.x, pk0); pk1 = fmaf(P[g*16+ 1], ka.y, pk1);
      pk0 = fmaf(P[g*16+ 2], ka.z, pk0); pk1 = fmaf(P[g*16+ 3], ka.w, pk1);
      pk0 = fmaf(P[g*16+ 4], kc.x, pk0); pk1 = fmaf(P[g*16+ 5], kc.y, pk1);
      pk0 = fmaf(P[g*16+ 6], kc.z, pk0); pk1 = fmaf(P[g*16+ 7], kc.w, pk1);
      pk0 = fmaf(P[g*16+ 8], ke.x, pk0); pk1 = fmaf(P[g*16+ 9], ke.y, pk1);
      pk0 = fmaf(P[g*16+10], ke.z, pk0); pk1 = fmaf(P[g*16+11], ke.w, pk1);
      pk0 = fmaf(P[g*16+12], kg.x, pk0); pk1 = fmaf(P[g*16+13], kg.y, pk1);
      pk0 = fmaf(P[g*16+14], kg.z, pk0); pk1 = fmaf(P[g*16+15], kg.w, pk1);
      sk0 = fmaf(S[g*16+ 0], ka.x, sk0); sk1 = fmaf(S[g*16+ 1], ka.y, sk1);
      sk0 = fmaf(S[g*16+ 2], ka.z, sk0); sk1 = fmaf(S[g*16+ 3], ka.w, sk1);
      sk0 = fmaf(S[g*16+ 4], kc.x, sk0); sk1 = fmaf(S[g*16+ 5], kc.y, sk1);
      sk0 = fmaf(S[g*16+ 6], kc.z, sk0); sk1 = fmaf(S[g*16+ 7], kc.w, sk1);
      sk0 = fmaf(S[g*16+ 8], ke.x, sk0); sk1 = fmaf(S[g*16+ 9], ke.y, sk1);
      sk0 = fmaf(S[g*16+10], ke.z, sk0); sk1 = fmaf(S[g*16+11], ke.w, sk1);
      sk0 = fmaf(S[g*16+12], kg.x, sk0); sk1 = fmaf(S[g*16+13], kg.y, sk1);
      sk0 = fmaf(S[g*16+14], kg.z, sk0); sk1 = fmaf(S[g*16+15], kg.w, sk1);
    }
    float cp = -at * (pk0 + pk1);
    float cs = fmaf(bt, vc, -at * (sk0 + sk1));
#pragma unroll
    for (int g = 0; g < 4; ++g) {
      float4 ka = *(const float4*)&kcur[g * 16 + 0];
      float4 kc = *(const float4*)&kcur[g * 16 + 4];
      float4 ke = *(const float4*)&kcur[g * 16 + 8];
      float4 kg = *(const float4*)&kcur[g * 16 + 12];
      P[g*16+ 0] = fmaf(cp, ka.x, P[g*16+ 0]); P[g*16+ 1] = fmaf(cp, ka.y, P[g*16+ 1]);
      P[g*16+ 2] = fmaf(cp, ka.z, P[g*16+ 2]); P[g*16+ 3] = fmaf(cp, ka.w, P[g*16+ 3]);
      P[g*16+ 4] = fmaf(cp, kc.x, P[g*16+ 4]); P[g*16+ 5] = fmaf(cp, kc.y, P[g*16+ 5]);
      P[g*16+ 6] = fmaf(cp, kc.z, P[g*16+ 6]); P[g*16+ 7] = fmaf(cp, kc.w, P[g*16+ 7]);
      P[g*16+ 8] = fmaf(cp, ke.x, P[g*16+ 8]); P[g*16+ 9] = fmaf(cp, ke.y, P[g*16+ 9]);
      P[g*16+10] = fmaf(cp, ke.z, P[g*16+10]); P[g*16+11] = fmaf(cp, ke.w, P[g*16+11]);
      P[g*16+12] = fmaf(cp, kg.x, P[g*16+12]); P[g*16+13] = fmaf(cp, kg.y, P[g*16+13]);
      P[g*16+14] = fmaf(cp, kg.z, P[g*16+14]); P[g*16+15] = fmaf(cp, kg.w, P[g*16+15]);
      S[g*16+ 0] = fmaf(cs, ka.x, S[g*16+ 0]); S[g*16+ 1] = fmaf(cs, ka.y, S[g*16+ 1]);
      S[g*16+ 2] = fmaf(cs, ka.z, S[g*16+ 2]); S[g*16+ 3] = fmaf(cs, ka.w, S[g*16+ 3]);
      S[g*16+ 4] = fmaf(cs, kc.x, S[g*16+ 4]); S[g*16+ 5] = fmaf(cs, kc.y, S[g*16+ 5]);
      S[g*16+ 6] = fmaf(cs, kc.z, S[g*16+ 6]); S[g*16+ 7] = fmaf(cs, kc.w, S[g*16+ 7]);
      S[g*16+ 8] = fmaf(cs, ke.x, S[g*16+ 8]); S[g*16+ 9] = fmaf(cs, ke.y, S[g*16+ 9]);
      S[g*16+10] = fmaf(cs, ke.z, S[g*16+10]); S[g*16+11] = fmaf(cs, ke.w, S[g*16+11]);
      S[g*16+12] = fmaf(cs, kg.x, S[g*16+12]); S[g*16+13] = fmaf(cs, kg.y, S[g*16+13]);
      S[g*16+14] = fmaf(cs, kg.z, S[g*16+14]); S[g*16+15] = fmaf(cs, kg.w, S[g*16+15]);
    }
  }
  float* po = Pbuf + (size_t)slot * 4096 + (size_t)lane * 64;
  float* so = Sbuf + (size_t)slot * 4096 + (size_t)lane * 64;
#pragma unroll
  for (int j4 = 0; j4 < 16; ++j4) {
    *(float4*)&po[j4 * 4] = make_float4(P[4 * j4], P[4 * j4 + 1], P[4 * j4 + 2], P[4 * j4 + 3]);
    *(float4*)&so[j4 * 4] = make_float4(S[4 * j4], S[4 * j4 + 1], S[4 * j4 + 2], S[4 * j4 + 3]);
  }
}

// ---- phase 2: fold nitems chunk pairs: (P,S) <- (P*Pc, S*Pc + Sc) ----
__global__ __launch_bounds__(256) void fold_kernel(
    const float* __restrict__ Pin, const float* __restrict__ Sin,
    float* __restrict__ Pout, float* __restrict__ Sout, int nitems) {
  __shared__ float Pa[64][68], Sa[64][68], Pc[64][68], Sc[64][68];
  const int tid = threadIdx.x;
  const int r0 = (tid >> 4) * 4, c0 = (tid & 15) * 4;
  for (int l = tid; l < 4096; l += 256) {
    int r = l >> 6, c = l & 63;
    Pa[r][c] = (r == c) ? 1.f : 0.f;
    Sa[r][c] = 0.f;
  }
  for (int item = 0; item < nitems; ++item) {
    const float* pg = Pin + ((size_t)blockIdx.x * nitems + item) * 4096;
    const float* sg = Sin + ((size_t)blockIdx.x * nitems + item) * 4096;
#pragma unroll
    for (int e = 0; e < 4; ++e) {
      int l = tid * 16 + e * 4;
      int r = l >> 6, c = l & 63;
      *(float4*)&Pc[r][c] = *(const float4*)&pg[l];
      *(float4*)&Sc[r][c] = *(const float4*)&sg[l];
    }
    __syncthreads();
    float accP[4][4] = {}, accS[4][4] = {};
#pragma unroll 4
    for (int j4 = 0; j4 < 16; ++j4) {
      float bmat[4][4];
#pragma unroll
      for (int jj = 0; jj < 4; ++jj) {
        float4 t = *(const float4*)&Pc[j4 * 4 + jj][c0];
        bmat[jj][0] = t.x; bmat[jj][1] = t.y; bmat[jj][2] = t.z; bmat[jj][3] = t.w;
      }
#pragma unroll
      for (int rr = 0; rr < 4; ++rr) {
        float4 tp = *(const float4*)&Pa[r0 + rr][j4 * 4];
        float4 ts = *(const float4*)&Sa[r0 + rr][j4 * 4];
        float ap[4] = {tp.x, tp.y, tp.z, tp.w};
        float as[4] = {ts.x, ts.y, ts.z, ts.w};
#pragma unroll
        for (int jj = 0; jj < 4; ++jj)
#pragma unroll
          for (int cc = 0; cc < 4; ++cc) {
            accP[rr][cc] = fmaf(ap[jj], bmat[jj][cc], accP[rr][cc]);
            accS[rr][cc] = fmaf(as[jj], bmat[jj][cc], accS[rr][cc]);
          }
      }
    }
#pragma unroll
    for (int rr = 0; rr < 4; ++rr)
#pragma unroll
      for (int cc = 0; cc < 4; ++cc) accS[rr][cc] += Sc[r0 + rr][c0 + cc];
    __syncthreads();
#pragma unroll
    for (int rr = 0; rr < 4; ++rr)
#pragma unroll
      for (int cc = 0; cc < 4; ++cc) {
        Pa[r0 + rr][c0 + cc] = accP[rr][cc];
        Sa[r0 + rr][c0 + cc] = accS[rr][cc];
      }
  }
  __syncthreads();
  float* po = Pout + (size_t)blockIdx.x * 4096;
  float* so = Sout + (size_t)blockIdx.x * 4096;
#pragma unroll
  for (int e = 0; e < 4; ++e) {
    int l = tid * 16 + e * 4;
    int r = l >> 6, c = l & 63;
    *(float4*)&po[l] = *(const float4*)&Pa[r][c];
    *(float4*)&so[l] = *(const float4*)&Sa[r][c];
  }
}

// ---- attn[b,t,h,i] = sum_j M[b,h,i,j] * q[b,t,h,j]  (bf16 out) ----
__global__ __launch_bounds__(256) void outm_kernel(
    const float* __restrict__ Mg, const float* __restrict__ q,
    u16* __restrict__ attn) {
  __shared__ float Ml[64][65];
  int bh = blockIdx.x;
  int tchunk = blockIdx.y;
  int b = bh >> 4, h = bh & 15;
  int tid = threadIdx.x;
  const float* mg = Mg + (size_t)bh * 4096;
#pragma unroll
  for (int e = 0; e < 16; ++e) {
    int l = tid + e * 256;
    Ml[l >> 6][l & 63] = mg[l];
  }
  __syncthreads();
  int lane = tid & 63, tt = tid >> 6;
  const float* qb = q + ((size_t)b * TQ_LEN + tchunk * 256) * DMODEL + h * HD;
  u16* ob = attn + ((size_t)b * TQ_LEN + tchunk * 256) * DMODEL + h * HD;
  for (int it = 0; it < 64; ++it) {
    int t = it * 4 + tt;
    const float* qr = qb + (size_t)t * DMODEL;
    float acc = 0.f;
#pragma unroll
    for (int j4 = 0; j4 < 16; ++j4) {
      float4 qv = *(const float4*)&qr[j4 * 4];
      acc += Ml[lane][j4 * 4 + 0] * qv.x + Ml[lane][j4 * 4 + 1] * qv.y +
             Ml[lane][j4 * 4 + 2] * qv.z + Ml[lane][j4 * 4 + 3] * qv.w;
    }
    ob[(size_t)t * DMODEL + lane] = f2bf(acc);
  }
}

extern "C" void kernel_launch(void* const* d_in, const int* in_sizes, int n_in,
                              void* d_out, int out_size, void* d_ws,
                              size_t ws_size, hipStream_t stream) {
  const float* query = (const float*)d_in[0];
  const float* key   = (const float*)d_in[1];
  const float* value = (const float*)d_in[2];
  const float* Wq    = (const float*)d_in[3];
  const float* Wk    = (const float*)d_in[4];
  const float* Wv    = (const float*)d_in[5];
  const float* Wo    = (const float*)d_in[6];
  const float* bo    = (const float*)d_in[7];
  const float* Wbeta = (const float*)d_in[8];
  const float* bbeta = (const float*)d_in[9];
  const float* Walpha= (const float*)d_in[10];
  const float* balpha= (const float*)d_in[11];
  const float* gq    = (const float*)d_in[12];
  const float* bq    = (const float*)d_in[13];
  const float* gk    = (const float*)d_in[14];
  const float* bk    = (const float*)d_in[15];
  float* out = (float*)d_out;

  const int MQ = BATCH * TQ_LEN;    // 8192
  const int MKV = BATCH * TKV_LEN;  // 16384
  const int NSLOT = 64 * NCHUNK;    // 2048

  // Workspace layout (float units). Peak 57,999,360 floats = 232.0 MB.
  float* ws = (float*)d_ws;
  size_t off = 0;
  u16* Wcat_bf = (u16*)(ws + off); off += (size_t)NKBA * DMODEL / 2;   // 589824
  u16* Wq_bf   = (u16*)(ws + off); off += (size_t)DMODEL * DMODEL / 2; // 262144
  u16* Wv_bf   = (u16*)(ws + off); off += (size_t)DMODEL * DMODEL / 2;
  u16* Wo_bf   = (u16*)(ws + off); off += (size_t)DMODEL * DMODEL / 2;
  u16* qbf = (u16*)(ws + off); size_t qbf_f = off; off += (size_t)MQ * DMODEL / 2;   // 4194304
  u16* kbf = (u16*)(ws + off); size_t kbf_f = off; off += (size_t)MKV * DMODEL / 2;  // 8388608
  u16* vbf = (u16*)(ws + off); size_t vbf_f = off; off += (size_t)MKV * DMODEL / 2;  // 8388608
  float* qp   = ws + off; off += (size_t)MQ * DMODEL;                  // 8388608
  float* kba  = ws + off; size_t kba_f = off; off += (size_t)MKV * NKBA; // 18874368
  u16* vpb = (u16*)(ws + off); off += (size_t)MKV * DMODEL / 2;        // 8388608
  // overlays on dead regions:
  float* Pbuf = ws + kbf_f;                    // 8388608 over kbf (dead after k GEMM)
  float* Sbuf = ws + vbf_f;                    // 8388608 over vbf (dead after v GEMM)
  float* Gp   = ws + qbf_f;                    // 1048576 ┐
  float* Gs   = ws + qbf_f + 1048576;          // 1048576 │ over qbf
  float* Fp   = ws + qbf_f + 2097152;          //  262144 │ (dead after q GEMM)
  float* beta = ws + qbf_f + 2359296;          //  262144 │
  float* alpha= ws + qbf_f + 2621440;          //  262144 │
  float* Mg   = ws + qbf_f + 2883584;          //  262144 ┘ total 3145728 <= 4194304
  u16* attn_bf = (u16*)(ws + kba_f);           // 4194304 over kba (dead after scan)

  // 1. weight + input casts
  wcat_bf_kernel<<<NKBA * DMODEL / 256, 256, 0, stream>>>(Wk, Wbeta, Walpha, Wcat_bf);
  cvt_bf16_kernel<<<DMODEL * DMODEL / 2048, 256, 0, stream>>>(Wq, Wq_bf);
  cvt_bf16_kernel<<<DMODEL * DMODEL / 2048, 256, 0, stream>>>(Wv, Wv_bf);
  cvt_bf16_kernel<<<DMODEL * DMODEL / 2048, 256, 0, stream>>>(Wo, Wo_bf);
  cvt_bf16_kernel<<<MQ * DMODEL / 2048, 256, 0, stream>>>(query, qbf);
  cvt_bf16_kernel<<<MKV * DMODEL / 2048, 256, 0, stream>>>(key, kbf);
  cvt_bf16_kernel<<<MKV * DMODEL / 2048, 256, 0, stream>>>(value, vbf);
  // 2. projections (bf16 MFMA; 1-D grid, XCD swizzle, nwg % 8 == 0)
  gemm_bt_bf16<false, false><<<(DMODEL / 128) * (MQ / 128), 256, 0, stream>>>(
      qbf, Wq_bf, nullptr, qp, MQ, DMODEL, DMODEL, DMODEL, DMODEL / 128);
  gemm_bt_bf16<false, false><<<(NKBA / 128) * (MKV / 128), 256, 0, stream>>>(
      kbf, Wcat_bf, nullptr, kba, MKV, NKBA, DMODEL, NKBA, NKBA / 128);
  gemm_bt_bf16<false, true><<<(DMODEL / 128) * (MKV / 128), 256, 0, stream>>>(
      vbf, Wv_bf, nullptr, vpb, MKV, DMODEL, DMODEL, DMODEL, DMODEL / 128);
  // 3. norms + gates (qbf dead from here -> beta/alpha/Mg overlay safe)
  ln_q_kernel<<<MQ * NH / 4, 256, 0, stream>>>(qp, gq, bq);
  ln_k_kernel<<<MKV * NH / 4, 256, 0, stream>>>(kba, gk, bk);
  sig_kernel<<<MKV * NH / 256, 256, 0, stream>>>(kba, bbeta, balpha, beta, alpha);
  // 4. chunked scan -> final state M
  chunk_scan_kernel<<<NSLOT, 64, 0, stream>>>(kba, vpb, beta, alpha, Pbuf, Sbuf);
  fold_kernel<<<NSLOT / 8, 256, 0, stream>>>(Pbuf, Sbuf, Gp, Gs, 8);
  fold_kernel<<<64, 256, 0, stream>>>(Gp, Gs, Fp, Mg, 4);
  // 5. attn = q @ M^T per (b,h)  (bf16 out, over dead kba)
  outm_kernel<<<dim3(64, TQ_LEN / 256), 256, 0, stream>>>(Mg, qp, attn_bf);
  // 6. out = attn @ Wo^T + bo
  gemm_bt_bf16<true, false><<<(DMODEL / 128) * (MQ / 128), 256, 0, stream>>>(
      attn_bf, Wo_bf, bo, out, MQ, DMODEL, DMODEL, DMODEL, DMODEL / 128);
  (void)in_sizes; (void)n_in; (void)out_size; (void)ws_size;
}